// Round 7
// baseline (401.489 us; speedup 1.0000x reference)
//
#include <hip/hip_runtime.h>
#include <stdint.h>

#pragma clang fp contract(off)

typedef int i32x4 __attribute__((ext_vector_type(4)));
typedef float f32x4 __attribute__((ext_vector_type(4)));
typedef unsigned char u8;

#define T_   4
#define B_   16
#define C_   512
#define HID_ 2048
#define NPIX 256
#define Z_   64            // T_*B_

// ---------------- workspace layout (bytes) ----------------
// AB coef: float2 per output row, rows ordered qkv(1536) proj(512) fc1(2048) fc2(512)
constexpr size_t OFF_AB      = 0;                        // 4608*8 = 36864
constexpr size_t OFF_PRESUM  = 65536;                    // 4*64*512 i32 = 512KB
constexpr size_t OFF_MASK    = OFF_PRESUM + 524288;      // u8[64][512] = 32KB
constexpr size_t OFF_WD      = OFF_MASK + 65536;
constexpr size_t SZ_QKVD = 1536*512;
constexpr size_t SZ_PD   = 512*512;
constexpr size_t SZ_F1D  = 2048*512;
constexpr size_t SZ_F2D  = 512*2048;
constexpr size_t OFF_QKV1 = OFF_WD;
constexpr size_t OFF_QKV0 = OFF_QKV1 + SZ_QKVD;
constexpr size_t OFF_P1   = OFF_QKV0 + SZ_QKVD;
constexpr size_t OFF_P0   = OFF_P1 + SZ_PD;
constexpr size_t OFF_F11  = OFF_P0 + SZ_PD;
constexpr size_t OFF_F10  = OFF_F11 + SZ_F1D;
constexpr size_t OFF_F21  = OFF_F10 + SZ_F1D;
constexpr size_t OFF_F20  = OFF_F21 + SZ_F2D;
constexpr size_t SPKB8    = (size_t)64*256*512;          // 8MB per 512-ch spike tensor
constexpr size_t OFF_SPK_A   = (OFF_F20 + SZ_F2D + 255) & ~(size_t)255;  // xs -> att (u8)
constexpr size_t OFF_SPK_QKV = OFF_SPK_A + SPKB8;        // [z][n][1536] u8 (24MB)
constexpr size_t OFF_SPK_E   = OFF_SPK_QKV + 3*SPKB8;    // h1 (8MB)
constexpr size_t OFF_H2      = OFF_SPK_E + SPKB8;        // h2 [z][n][2048] u8 (32MB)

// ---------------- prep: per-row absmax -> pow2 scale -> 2-digit i8 quant + folded BN ----------------
// One wave per output row.  w ~= (d1*256 + d0)/S with S = 2^sh chosen so max|w|*S <= 32639.
// Exact i32 accumulation downstream; only error is weight rounding <= 0.5/S.
// Folded epilogue coefs: val = q_total * A + B,  A = sc/S,  B = (bias - m)*sc + beta.
__global__ __launch_bounds__(256) void prep_quant_kernel(
        const float* __restrict__ q_w, const float* __restrict__ k_w,
        const float* __restrict__ v_w, const float* __restrict__ p_w,
        const float* __restrict__ f1_w, const float* __restrict__ f2_w,
        const float* __restrict__ q_bn, const float* __restrict__ k_bn,
        const float* __restrict__ v_bn, const float* __restrict__ p_bn,
        const float* __restrict__ f1_bn, const float* __restrict__ f2_bn,
        const float* __restrict__ p_b, const float* __restrict__ f1_b,
        const float* __restrict__ f2_b, char* ws) {
    int wv = threadIdx.x >> 6, lane = threadIdx.x & 63;
    int r = blockIdx.x * 4 + wv;            // 0..4607
    const float* wsrc; const float* bn; const float* bias;
    char *d1, *d0; int Cin, Cn, o;
    if (r < 512)        { o=r;       wsrc=q_w  + (size_t)o*512;  bn=q_bn;  bias=nullptr; Cin=512;  Cn=512;
                          d1=ws+OFF_QKV1+(size_t)r*512;      d0=ws+OFF_QKV0+(size_t)r*512; }
    else if (r < 1024)  { o=r-512;   wsrc=k_w  + (size_t)o*512;  bn=k_bn;  bias=nullptr; Cin=512;  Cn=512;
                          d1=ws+OFF_QKV1+(size_t)r*512;      d0=ws+OFF_QKV0+(size_t)r*512; }
    else if (r < 1536)  { o=r-1024;  wsrc=v_w  + (size_t)o*512;  bn=v_bn;  bias=nullptr; Cin=512;  Cn=512;
                          d1=ws+OFF_QKV1+(size_t)r*512;      d0=ws+OFF_QKV0+(size_t)r*512; }
    else if (r < 2048)  { o=r-1536;  wsrc=p_w  + (size_t)o*512;  bn=p_bn;  bias=p_b;     Cin=512;  Cn=512;
                          d1=ws+OFF_P1+(size_t)o*512;        d0=ws+OFF_P0+(size_t)o*512; }
    else if (r < 4096)  { o=r-2048;  wsrc=f1_w + (size_t)o*512;  bn=f1_bn; bias=f1_b;    Cin=512;  Cn=2048;
                          d1=ws+OFF_F11+(size_t)o*512;       d0=ws+OFF_F10+(size_t)o*512; }
    else if (r < 4608)  { o=r-4096;  wsrc=f2_w + (size_t)o*2048; bn=f2_bn; bias=f2_b;    Cin=2048; Cn=512;
                          d1=ws+OFF_F21+(size_t)o*2048;      d0=ws+OFF_F20+(size_t)o*2048; }
    else return;

    float mx = 0.0f;
    for (int c = lane; c < Cin; c += 64) mx = fmaxf(mx, fabsf(wsrc[c]));
    #pragma unroll
    for (int off = 32; off; off >>= 1) mx = fmaxf(mx, __shfl_xor(mx, off));

    int E; float mant = frexpf(mx, &E);          // mx = mant*2^E, mant in [0.5,1)
    int sh = (ldexpf(mant, 15) > 32639.0f) ? (14 - E) : (15 - E);
    if (mx == 0.0f) sh = 0;
    float S = ldexpf(1.0f, sh);

    for (int c = lane; c < Cin; c += 64) {
        int q = __float2int_rn(wsrc[c] * S);
        int t0 = ((q + 128) & 255) - 128;        // low digit in [-128,127]
        int t1 = (q - t0) >> 8;                  // high digit, exact, in [-128,127]
        d0[c] = (char)t0;
        d1[c] = (char)t1;
    }
    if (lane == 0) {
        float g  = bn[o];
        float be = bn[Cn + o];
        float m  = bn[2 * Cn + o];
        float vv = bn[3 * Cn + o];
        float sc = g / sqrtf(vv + 1e-5f);
        float bv = bias ? bias[o] : 0.0f;
        float2* ab = (float2*)(ws + OFF_AB) + r;
        *ab = make_float2(sc * ldexpf(1.0f, -sh), (bv - m) * sc + be);
    }
}

// ---------------- LIF + transpose: y[T,B,Cf,N] f32 -> spk[z][n][c] u8 ----------------
__global__ __launch_bounds__(256) void lif_transpose_kernel(
        const float* __restrict__ y, u8* __restrict__ spk, int Cf) {
    __shared__ __align__(16) u8 tile[256 * 80];   // [t*64+nn][80]
    int b  = blockIdx.z;
    int c0 = blockIdx.y * 64;
    int n0 = blockIdx.x * 64;
    int tid = threadIdx.x;
    int nn = tid & 63;
    int cg = tid >> 6;
    size_t tstride = (size_t)B_ * Cf * NPIX;
    for (int e = 0; e < 16; ++e) {
        int ci = cg * 16 + e;
        size_t base = ((size_t)b * Cf + c0 + ci) * NPIX + n0 + nn;
        float v = 0.0f;
        #pragma unroll
        for (int t = 0; t < T_; ++t) {
            float x = y[base + (size_t)t * tstride];
            v = v + (x - v) * 0.5f;
            u8 s = 0;
            if (v >= 1.0f) { s = 1; v = 0.0f; }
            tile[(t * 64 + nn) * 80 + ci] = s;
        }
    }
    __syncthreads();
    int t = tid >> 6, n2 = tid & 63;
    const u8* srow = &tile[(t * 64 + n2) * 80];
    u8* drow = spk + ((size_t)((t * B_ + b) * NPIX) + n0 + n2) * Cf + c0;
    #pragma unroll
    for (int kk = 0; kk < 4; ++kk)
        *(uint4*)(drow + kk * 16) = *(const uint4*)(srow + kk * 16);
}

// ---------------- kv presum: integer counts of (k&v) over n-quarter (u8 spikes) ----------------
__global__ void kv_presum_kernel(const u8* __restrict__ qkv, int* __restrict__ presum4) {
    int z  = blockIdx.x >> 2;
    int nq = blockIdx.x & 3;
    int tid = threadIdx.x;
    if (tid >= 128) return;                       // 128 uints cover 512 k-channels
    const uint* base = (const uint*)(qkv + (size_t)z * NPIX * 1536 + (size_t)nq * 64 * 1536);
    int s0 = 0, s1 = 0, s2 = 0, s3 = 0;
    for (int n = 0; n < 64; ++n) {
        uint a = base[n * 384 + 128 + tid];   // k bytes 512..1023
        uint b = base[n * 384 + 256 + tid];   // v bytes 1024..1535
        uint c = a & b;
        s0 += c & 1; s1 += (c >> 8) & 1; s2 += (c >> 16) & 1; s3 += (c >> 24) & 1;
    }
    int o = ((nq * Z_ + z) << 9) + 4 * tid;
    presum4[o] = s0; presum4[o + 1] = s1; presum4[o + 2] = s2; presum4[o + 3] = s3;
}

// ---------------- kv LIF (vth=0.5) -> mask u8 ----------------
__global__ void kv_lif_mask_kernel(const int* __restrict__ presum4, u8* __restrict__ mask) {
    int i = blockIdx.x * 256 + threadIdx.x;   // 8192 = B_*C_
    int b = i >> 9, c = i & (C_ - 1);
    float v = 0.0f;
    #pragma unroll
    for (int t = 0; t < T_; ++t) {
        int z = t * B_ + b;
        int s = presum4[(z << 9) + c] + presum4[((Z_ + z) << 9) + c]
              + presum4[((2 * Z_ + z) << 9) + c] + presum4[((3 * Z_ + z) << 9) + c];
        float x = (float)s;                   // exact integer <= 256
        v = v + (x - v) * 0.5f;
        u8 m = 0;
        if (v >= 0.5f) { m = 0xFF; v = 0.0f; }
        mask[(z << 9) + c] = m;
    }
}

// ---------------- att = q & mask (q strided 1536B, out compact 512B) ----------------
__global__ void att_apply_kernel(const u8* __restrict__ qkv, const u8* __restrict__ mask,
                                 u8* __restrict__ att) {
    size_t i = (size_t)blockIdx.x * 256 + threadIdx.x;  // over 64*256*64 uint2-groups
    int z   = (int)(i >> 14);
    int rem = (int)(i & 16383);
    int n   = rem >> 6;
    int c8  = rem & 63;
    uint2 qv = *(const uint2*)(qkv + ((size_t)z * NPIX + n) * 1536 + c8 * 8);
    uint2 mv = *(const uint2*)(mask + (size_t)z * C_ + c8 * 8);
    uint2 r;
    r.x = qv.x & mv.x;
    r.y = qv.y & mv.y;
    *(uint2*)(att + ((size_t)z * NPIX + n) * 512 + c8 * 8) = r;
}

// ---------------- fused i8 MFMA GEMM: A LDS-staged, B global-direct, BN/LIF fused ----------------
// Round-6 post-mortem: per-block-step wall (~1969 cyc) == LDS traffic (88KB @ ~90 B/cyc).
// LDS is the pipe to unload.  B rows are wave-exclusive -> load global->reg (4x dwordx4/step,
// depth-1 prefetch, compiler vmcnt).  Safe NOW (unlike round-1 f16): u8 spikes halve the
// per-b B panel (fc2: 2MB, fc1: 512KB) -> L2-resident.  LDS/block-step: 88KB -> 40KB
// (A reads 32KB + A DMA 8KB); LDS size 49KB -> 16KB/block.
// Grid reorder for L2 slicing: id = px + 4*(oy + nOy*b), b OUTERMOST.  4*nOy%8==0 so
// XCD = (px+4*oy)%8: each XCD serves one p-quarter (px=x%4) and one oy-parity -> per-XCD
// working set (B-quarter of current b + A-parity slice) fits 4MB L2 for every layer.
// 512 thr = 8 waves, wave w = (oh=w>>2 o-half, zz=w&3); block tile 64o x 64p x 4z; 2 blk/CU.
// mode 0: spikes only; 1: f32 y(+res) AND spikes; 2: f32(+res) only.
// vhout (qkv only): v-section (o0>=1024) spikes also stored as f32 [z][h][n][64].
__global__ __launch_bounds__(512, 4) void gemm_fused_kernel(
        const u8* __restrict__ S,      // [64][256][Cin] u8 spikes
        const char* __restrict__ Wd1,  // [Cout][Cin] high digit
        const char* __restrict__ Wd0,  // [Cout][Cin] low digit
        const float2* __restrict__ AB, // [Cout] folded (A,B) coefs
        const float* res,              // [z][Cout][256] or null (may alias yout)
        float* yout,                   // [z][Cout][256] (modes 1,2)
        u8* spkout,                    // [z][n][Cout]   (modes 0,1)
        float* vhout,                  // vh f32 out or null
        int Cin, int Cout, int mode) {
    __shared__ __align__(16) char lds[16384];   // 2 stages x (Ad1 4K | Ad0 4K)
    float* ldsf = (float*)lds;
    const int tid  = threadIdx.x;
    const int lane = tid & 63;
    const int w    = tid >> 6;           // wave index 0..7
    const int oh   = w >> 2;             // o-half (0,1)
    const int zz   = w & 3;              // timestep
    const int r15 = lane & 15, quad = lane >> 4;
    const int id = blockIdx.x;
    const int nOy = Cout >> 6;
    const int px  = id & 3;
    const int rest = id >> 2;
    const int oy  = rest % nOy;
    const int b   = rest / nOy;
    const int o0 = oy * 64;
    const int p0 = px * 64;
    const int zt = zz * B_ + b;

    i32x4 acc1[2][4], acc2[2][4];
    #pragma unroll
    for (int a = 0; a < 2; ++a)
        #pragma unroll
        for (int c = 0; c < 4; ++c) {
            acc1[a][c] = (i32x4){0, 0, 0, 0};
            acc2[a][c] = (i32x4){0, 0, 0, 0};
        }

    const int srow = lane >> 2;   // staging row within 16-row group (0..15)
    const int sj   = lane & 3;    // staging 16B chunk slot (0..3)

    // ---- A staging: 1 global_load_lds per wave per stage (8KB/stage total) ----
    const char* ssrc;
    int sdst;
    {
        int g = w;                      // 0..7
        if (g < 4) {                    // Ad1: rows g*16..g*16+15
            int m = g * 16 + srow;
            ssrc = Wd1 + (size_t)(o0 + m) * Cin + ((sj ^ ((m >> 1) & 3)) << 4);
        } else {                        // Ad0
            int m = (g - 4) * 16 + srow;
            ssrc = Wd0 + (size_t)(o0 + m) * Cin + ((sj ^ ((m >> 1) & 3)) << 4);
        }
        sdst = g * 1024;
    }

    auto stage = [&](int k0, int st) {
        __builtin_amdgcn_global_load_lds(
            (const __attribute__((address_space(1))) void*)(uintptr_t)(const void*)(ssrc + k0),
            (__attribute__((address_space(3))) void*)(uintptr_t)(void*)(lds + st * 8192 + sdst),
            16, 0, 0);
    };

    // ---- A ds_read offsets (wave's 32-row half) ----
    int offA[2], offL[2];
    #pragma unroll
    for (int mt = 0; mt < 2; ++mt) {
        int m = oh * 32 + mt * 16 + r15;
        offA[mt] = m * 64 + ((quad ^ ((m >> 1) & 3)) << 4);
        offL[mt] = 4096 + offA[mt];
    }

    // ---- B direct-global bases (wave-exclusive rows; 64B contiguous per row per step) ----
    const char* bsrc[4];
    #pragma unroll
    for (int nt = 0; nt < 4; ++nt)
        bsrc[nt] = (const char*)S + ((size_t)(zt * NPIX + p0 + nt * 16 + r15)) * Cin + quad * 16;

    auto loadB = [&](int k0, i32x4* bf) {
        #pragma unroll
        for (int nt = 0; nt < 4; ++nt)
            bf[nt] = *(const i32x4*)(bsrc[nt] + k0);
    };

    auto compute = [&](int bufbase, const i32x4* bf) {
        i32x4 af[2], al[2];
        #pragma unroll
        for (int mt = 0; mt < 2; ++mt) {
            af[mt] = *(const i32x4*)(lds + bufbase + offA[mt]);
            al[mt] = *(const i32x4*)(lds + bufbase + offL[mt]);
        }
        #pragma unroll
        for (int mt = 0; mt < 2; ++mt)
            #pragma unroll
            for (int nt = 0; nt < 4; ++nt) {
                acc1[mt][nt] = __builtin_amdgcn_mfma_i32_16x16x64_i8(af[mt], bf[nt], acc1[mt][nt], 0, 0, 0);
                acc2[mt][nt] = __builtin_amdgcn_mfma_i32_16x16x64_i8(al[mt], bf[nt], acc2[mt][nt], 0, 0, 0);
            }
    };

    const int nIter = Cin >> 6;   // 8 or 32, always even
    i32x4 bcur[4], bnxt[4];
    stage(0, 0);
    loadB(0, bcur);
    int k = 64;
    for (int i = 0; i < nIter; i += 2) {
        __syncthreads();
        if (i + 1 < nIter) { stage(k, 1); loadB(k, bnxt); }
        k += 64;
        compute(0, bcur);
        __syncthreads();
        if (i + 2 < nIter) { stage(k, 0); loadB(k, bcur); }
        k += 64;
        compute(8192, bnxt);
    }

    // combine digits + folded BN (+res)
    f32x4 yv[2][4];
    #pragma unroll
    for (int mt = 0; mt < 2; ++mt) {
        int obl = o0 + oh * 32 + mt * 16 + quad * 4;
        float av[4], bv[4];
        #pragma unroll
        for (int r = 0; r < 4; ++r) {
            float2 abv = AB[obl + r];
            av[r] = abv.x; bv[r] = abv.y;
        }
        #pragma unroll
        for (int nt = 0; nt < 4; ++nt) {
            int p = p0 + nt * 16 + r15;
            #pragma unroll
            for (int r = 0; r < 4; ++r) {
                int qi = (acc1[mt][nt][r] << 8) + acc2[mt][nt][r];   // exact, < 2^24
                float val = fmaf((float)qi, av[r], bv[r]);
                if (mode != 0) {
                    size_t idx = ((size_t)zt * Cout + obl + r) * NPIX + p;
                    val += res[idx];
                }
                yv[mt][nt][r] = val;
            }
        }
    }
    if (mode != 0) {
        #pragma unroll
        for (int mt = 0; mt < 2; ++mt) {
            int ob = o0 + oh * 32 + mt * 16 + quad * 4;
            #pragma unroll
            for (int nt = 0; nt < 4; ++nt) {
                int p = p0 + nt * 16 + r15;
                #pragma unroll
                for (int r = 0; r < 4; ++r)
                    yout[((size_t)zt * Cout + ob + r) * NPIX + p] = yv[mt][nt][r];
            }
        }
    }
    if (mode != 2) {
        // LIF across the 4 timesteps via LDS, four 16-pixel phases
        __syncthreads();
        const int o2 = tid & 63;            // out-channel within block (0..63)
        const int pj = tid >> 6;            // p-group (0..7), 2 pixels each
        const bool dovh = (vhout != nullptr) && (o0 >= 1024);
        const int hsec = (o0 - 1024) >> 6;
        #pragma unroll
        for (int ph = 0; ph < 4; ++ph) {
            #pragma unroll
            for (int mt = 0; mt < 2; ++mt) {
                int ol = oh * 32 + mt * 16 + quad * 4;
                #pragma unroll
                for (int r = 0; r < 4; ++r)
                    ldsf[zz * 1088 + (ol + r) * 17 + r15] = yv[mt][ph][r];
            }
            __syncthreads();
            u8 sp[4][2];
            #pragma unroll
            for (int jj = 0; jj < 2; ++jj) {
                int p = pj * 2 + jj;
                float v = 0.0f;
                #pragma unroll
                for (int t = 0; t < T_; ++t) {
                    float x = ldsf[t * 1088 + o2 * 17 + p];
                    v = v + (x - v) * 0.5f;
                    u8 s = 0;
                    if (v >= 1.0f) { s = 1; v = 0.0f; }
                    sp[t][jj] = s;
                }
            }
            #pragma unroll
            for (int t = 0; t < T_; ++t)
                #pragma unroll
                for (int jj = 0; jj < 2; ++jj) {
                    int p = p0 + ph * 16 + pj * 2 + jj;
                    spkout[((size_t)((t * B_ + b) * NPIX + p)) * Cout + o0 + o2] = sp[t][jj];
                    if (dovh)
                        vhout[((((size_t)(t * B_ + b)) * 8 + hsec) * NPIX + p) * 64 + o2] =
                            sp[t][jj] ? 1.0f : 0.0f;
                }
            __syncthreads();
        }
    }
}

extern "C" void kernel_launch(void* const* d_in, const int* in_sizes, int n_in,
                              void* d_out, int out_size, void* d_ws, size_t ws_size,
                              hipStream_t stream) {
    (void)in_sizes; (void)n_in; (void)out_size; (void)ws_size;
    const float* x       = (const float*)d_in[0];
    const float* q_w     = (const float*)d_in[1];
    const float* k_w     = (const float*)d_in[2];
    const float* v_w     = (const float*)d_in[3];
    const float* proj_w  = (const float*)d_in[4];
    const float* proj_b  = (const float*)d_in[5];
    const float* fc1_w   = (const float*)d_in[6];
    const float* fc1_b   = (const float*)d_in[7];
    const float* fc2_w   = (const float*)d_in[8];
    const float* fc2_b   = (const float*)d_in[9];
    const float* q_bn    = (const float*)d_in[10];
    const float* k_bn    = (const float*)d_in[11];
    const float* v_bn    = (const float*)d_in[12];
    const float* proj_bn = (const float*)d_in[13];
    const float* fc1_bn  = (const float*)d_in[14];
    const float* fc2_bn  = (const float*)d_in[15];

    char* ws = (char*)d_ws;
    float2* abb   = (float2*)(ws + OFF_AB);
    int*   presum4 = (int*)(ws + OFF_PRESUM);
    u8*    maskp   = (u8*)(ws + OFF_MASK);
    const char *qkv1 = ws + OFF_QKV1, *qkv0 = ws + OFF_QKV0;
    const char *p1 = ws + OFF_P1,   *p0d = ws + OFF_P0;
    const char *f11 = ws + OFF_F11, *f10 = ws + OFF_F10;
    const char *f21 = ws + OFF_F21, *f20 = ws + OFF_F20;
    u8* spkA   = (u8*)(ws + OFF_SPK_A);    // xs -> att
    u8* spkQKV = (u8*)(ws + OFF_SPK_QKV);  // [z][n][1536]
    u8* spkE   = (u8*)(ws + OFF_SPK_E);    // h1
    u8* h2     = (u8*)(ws + OFF_H2);       // h2 [z][n][2048]

    float* out1 = (float*)d_out;
    float* out2 = out1 + 8388608;
    float* x_attn = out1;                 // x_attn lives in out1 until fc2 overwrites in-place

    // prep: quantize all weights + fold BN (1 launch)
    prep_quant_kernel<<<1152, 256, 0, stream>>>(q_w, k_w, v_w, proj_w, fc1_w, fc2_w,
                                                q_bn, k_bn, v_bn, proj_bn, fc1_bn, fc2_bn,
                                                proj_b, fc1_b, fc2_b, ws);

    dim3 gLT(4, 8, 16);       // lif_transpose on x (Cf=512)

    // shortcut LIF on x -> xs spikes [z][n][c] u8
    lif_transpose_kernel<<<gLT, 256, 0, stream>>>(x, spkA, C_);

    // q+k+v fused: GEMM+BN+LIF -> spikes [z][n][1536]; v-section also writes vh f32 (out2)
    gemm_fused_kernel<<<24 * 64, 512, 0, stream>>>(spkA, qkv1, qkv0, abb,
                                                   nullptr, nullptr, spkQKV, out2, C_, 1536, 0);

    // kv reduce + talking-heads LIF + att mask
    kv_presum_kernel<<<256, 256, 0, stream>>>(spkQKV, presum4);
    kv_lif_mask_kernel<<<32, 256, 0, stream>>>(presum4, maskp);
    att_apply_kernel<<<4096, 256, 0, stream>>>(spkQKV, maskp, spkA);   // att into A (xs dead)

    // proj: GEMM(att)+bias+BN + x residual -> x_attn f32 AND h1 spikes
    gemm_fused_kernel<<<8 * 64, 512, 0, stream>>>(spkA, p1, p0d, abb + 1536,
                                                  x, x_attn, spkE, nullptr, C_, C_, 1);

    // fc1: GEMM+bias+BN+LIF -> h2 spikes
    gemm_fused_kernel<<<32 * 64, 512, 0, stream>>>(spkE, f11, f10, abb + 2048,
                                                   nullptr, nullptr, h2, nullptr, C_, HID_, 0);

    // fc2: GEMM+bias+BN + x_attn residual -> out1 (in place over x_attn)
    gemm_fused_kernel<<<8 * 64, 512, 0, stream>>>(h2, f21, f20, abb + 4096,
                                                  x_attn, out1, nullptr, nullptr, HID_, C_, 2);
}

// Round 8
// 301.718 us; speedup vs baseline: 1.3307x; 1.3307x over previous
//
#include <hip/hip_runtime.h>
#include <stdint.h>

#pragma clang fp contract(off)

typedef int i32x4 __attribute__((ext_vector_type(4)));
typedef float f32x4 __attribute__((ext_vector_type(4)));
typedef unsigned char u8;

#define T_   4
#define B_   16
#define C_   512
#define HID_ 2048
#define NPIX 256
#define Z_   64            // T_*B_

// ---------------- workspace layout (bytes) ----------------
// AB coef: float2 per output row, rows ordered qkv(1536) proj(512) fc1(2048) fc2(512)
constexpr size_t OFF_AB      = 0;                        // 4608*8 = 36864
constexpr size_t OFF_PRESUM  = 65536;                    // 4*64*512 i32 = 512KB
constexpr size_t OFF_MASK    = OFF_PRESUM + 524288;      // u8[64][512] = 32KB
constexpr size_t OFF_WD      = OFF_MASK + 65536;
constexpr size_t SZ_QKVD = 1536*512;
constexpr size_t SZ_PD   = 512*512;
constexpr size_t SZ_F1D  = 2048*512;
constexpr size_t SZ_F2D  = 512*2048;
constexpr size_t OFF_QKV1 = OFF_WD;
constexpr size_t OFF_QKV0 = OFF_QKV1 + SZ_QKVD;
constexpr size_t OFF_P1   = OFF_QKV0 + SZ_QKVD;
constexpr size_t OFF_P0   = OFF_P1 + SZ_PD;
constexpr size_t OFF_F11  = OFF_P0 + SZ_PD;
constexpr size_t OFF_F10  = OFF_F11 + SZ_F1D;
constexpr size_t OFF_F21  = OFF_F10 + SZ_F1D;
constexpr size_t OFF_F20  = OFF_F21 + SZ_F2D;
constexpr size_t SPKB8    = (size_t)64*256*512;          // 8MB per 512-ch spike tensor
constexpr size_t OFF_SPK_A   = (OFF_F20 + SZ_F2D + 255) & ~(size_t)255;  // xs -> att (u8)
constexpr size_t OFF_SPK_QKV = OFF_SPK_A + SPKB8;        // [z][n][1536] u8 (24MB)
constexpr size_t OFF_SPK_E   = OFF_SPK_QKV + 3*SPKB8;    // h1 (8MB)
constexpr size_t OFF_H2      = OFF_SPK_E + SPKB8;        // h2 [z][n][2048] u8 (32MB)

// ---------------- prep: per-row absmax -> pow2 scale -> 2-digit i8 quant + folded BN ----------------
// One wave per output row.  w ~= (d1*256 + d0)/S with S = 2^sh chosen so max|w|*S <= 32639.
// Exact i32 accumulation downstream; only error is weight rounding <= 0.5/S.
// Folded epilogue coefs: val = q_total * A + B,  A = sc/S,  B = (bias - m)*sc + beta.
__global__ __launch_bounds__(256) void prep_quant_kernel(
        const float* __restrict__ q_w, const float* __restrict__ k_w,
        const float* __restrict__ v_w, const float* __restrict__ p_w,
        const float* __restrict__ f1_w, const float* __restrict__ f2_w,
        const float* __restrict__ q_bn, const float* __restrict__ k_bn,
        const float* __restrict__ v_bn, const float* __restrict__ p_bn,
        const float* __restrict__ f1_bn, const float* __restrict__ f2_bn,
        const float* __restrict__ p_b, const float* __restrict__ f1_b,
        const float* __restrict__ f2_b, char* ws) {
    int wv = threadIdx.x >> 6, lane = threadIdx.x & 63;
    int r = blockIdx.x * 4 + wv;            // 0..4607
    const float* wsrc; const float* bn; const float* bias;
    char *d1, *d0; int Cin, Cn, o;
    if (r < 512)        { o=r;       wsrc=q_w  + (size_t)o*512;  bn=q_bn;  bias=nullptr; Cin=512;  Cn=512;
                          d1=ws+OFF_QKV1+(size_t)r*512;      d0=ws+OFF_QKV0+(size_t)r*512; }
    else if (r < 1024)  { o=r-512;   wsrc=k_w  + (size_t)o*512;  bn=k_bn;  bias=nullptr; Cin=512;  Cn=512;
                          d1=ws+OFF_QKV1+(size_t)r*512;      d0=ws+OFF_QKV0+(size_t)r*512; }
    else if (r < 1536)  { o=r-1024;  wsrc=v_w  + (size_t)o*512;  bn=v_bn;  bias=nullptr; Cin=512;  Cn=512;
                          d1=ws+OFF_QKV1+(size_t)r*512;      d0=ws+OFF_QKV0+(size_t)r*512; }
    else if (r < 2048)  { o=r-1536;  wsrc=p_w  + (size_t)o*512;  bn=p_bn;  bias=p_b;     Cin=512;  Cn=512;
                          d1=ws+OFF_P1+(size_t)o*512;        d0=ws+OFF_P0+(size_t)o*512; }
    else if (r < 4096)  { o=r-2048;  wsrc=f1_w + (size_t)o*512;  bn=f1_bn; bias=f1_b;    Cin=512;  Cn=2048;
                          d1=ws+OFF_F11+(size_t)o*512;       d0=ws+OFF_F10+(size_t)o*512; }
    else if (r < 4608)  { o=r-4096;  wsrc=f2_w + (size_t)o*2048; bn=f2_bn; bias=f2_b;    Cin=2048; Cn=512;
                          d1=ws+OFF_F21+(size_t)o*2048;      d0=ws+OFF_F20+(size_t)o*2048; }
    else return;

    float mx = 0.0f;
    for (int c = lane; c < Cin; c += 64) mx = fmaxf(mx, fabsf(wsrc[c]));
    #pragma unroll
    for (int off = 32; off; off >>= 1) mx = fmaxf(mx, __shfl_xor(mx, off));

    int E; float mant = frexpf(mx, &E);          // mx = mant*2^E, mant in [0.5,1)
    int sh = (ldexpf(mant, 15) > 32639.0f) ? (14 - E) : (15 - E);
    if (mx == 0.0f) sh = 0;
    float S = ldexpf(1.0f, sh);

    for (int c = lane; c < Cin; c += 64) {
        int q = __float2int_rn(wsrc[c] * S);
        int t0 = ((q + 128) & 255) - 128;        // low digit in [-128,127]
        int t1 = (q - t0) >> 8;                  // high digit, exact, in [-128,127]
        d0[c] = (char)t0;
        d1[c] = (char)t1;
    }
    if (lane == 0) {
        float g  = bn[o];
        float be = bn[Cn + o];
        float m  = bn[2 * Cn + o];
        float vv = bn[3 * Cn + o];
        float sc = g / sqrtf(vv + 1e-5f);
        float bv = bias ? bias[o] : 0.0f;
        float2* ab = (float2*)(ws + OFF_AB) + r;
        *ab = make_float2(sc * ldexpf(1.0f, -sh), (bv - m) * sc + be);
    }
}

// ---------------- LIF + transpose: y[T,B,Cf,N] f32 -> spk[z][n][c] u8 ----------------
__global__ __launch_bounds__(256) void lif_transpose_kernel(
        const float* __restrict__ y, u8* __restrict__ spk, int Cf) {
    __shared__ __align__(16) u8 tile[256 * 80];   // [t*64+nn][80]
    int b  = blockIdx.z;
    int c0 = blockIdx.y * 64;
    int n0 = blockIdx.x * 64;
    int tid = threadIdx.x;
    int nn = tid & 63;
    int cg = tid >> 6;
    size_t tstride = (size_t)B_ * Cf * NPIX;
    for (int e = 0; e < 16; ++e) {
        int ci = cg * 16 + e;
        size_t base = ((size_t)b * Cf + c0 + ci) * NPIX + n0 + nn;
        float v = 0.0f;
        #pragma unroll
        for (int t = 0; t < T_; ++t) {
            float x = y[base + (size_t)t * tstride];
            v = v + (x - v) * 0.5f;
            u8 s = 0;
            if (v >= 1.0f) { s = 1; v = 0.0f; }
            tile[(t * 64 + nn) * 80 + ci] = s;
        }
    }
    __syncthreads();
    int t = tid >> 6, n2 = tid & 63;
    const u8* srow = &tile[(t * 64 + n2) * 80];
    u8* drow = spk + ((size_t)((t * B_ + b) * NPIX) + n0 + n2) * Cf + c0;
    #pragma unroll
    for (int kk = 0; kk < 4; ++kk)
        *(uint4*)(drow + kk * 16) = *(const uint4*)(srow + kk * 16);
}

// ---------------- kv presum: integer counts of (k&v) over n-quarter (u8 spikes) ----------------
__global__ void kv_presum_kernel(const u8* __restrict__ qkv, int* __restrict__ presum4) {
    int z  = blockIdx.x >> 2;
    int nq = blockIdx.x & 3;
    int tid = threadIdx.x;
    if (tid >= 128) return;                       // 128 uints cover 512 k-channels
    const uint* base = (const uint*)(qkv + (size_t)z * NPIX * 1536 + (size_t)nq * 64 * 1536);
    int s0 = 0, s1 = 0, s2 = 0, s3 = 0;
    for (int n = 0; n < 64; ++n) {
        uint a = base[n * 384 + 128 + tid];   // k bytes 512..1023
        uint b = base[n * 384 + 256 + tid];   // v bytes 1024..1535
        uint c = a & b;
        s0 += c & 1; s1 += (c >> 8) & 1; s2 += (c >> 16) & 1; s3 += (c >> 24) & 1;
    }
    int o = ((nq * Z_ + z) << 9) + 4 * tid;
    presum4[o] = s0; presum4[o + 1] = s1; presum4[o + 2] = s2; presum4[o + 3] = s3;
}

// ---------------- kv LIF (vth=0.5) -> mask u8 ----------------
__global__ void kv_lif_mask_kernel(const int* __restrict__ presum4, u8* __restrict__ mask) {
    int i = blockIdx.x * 256 + threadIdx.x;   // 8192 = B_*C_
    int b = i >> 9, c = i & (C_ - 1);
    float v = 0.0f;
    #pragma unroll
    for (int t = 0; t < T_; ++t) {
        int z = t * B_ + b;
        int s = presum4[(z << 9) + c] + presum4[((Z_ + z) << 9) + c]
              + presum4[((2 * Z_ + z) << 9) + c] + presum4[((3 * Z_ + z) << 9) + c];
        float x = (float)s;                   // exact integer <= 256
        v = v + (x - v) * 0.5f;
        u8 m = 0;
        if (v >= 0.5f) { m = 0xFF; v = 0.0f; }
        mask[(z << 9) + c] = m;
    }
}

// ---------------- att = q & mask (q strided 1536B, out compact 512B) ----------------
__global__ void att_apply_kernel(const u8* __restrict__ qkv, const u8* __restrict__ mask,
                                 u8* __restrict__ att) {
    size_t i = (size_t)blockIdx.x * 256 + threadIdx.x;  // over 64*256*64 uint2-groups
    int z   = (int)(i >> 14);
    int rem = (int)(i & 16383);
    int n   = rem >> 6;
    int c8  = rem & 63;
    uint2 qv = *(const uint2*)(qkv + ((size_t)z * NPIX + n) * 1536 + c8 * 8);
    uint2 mv = *(const uint2*)(mask + (size_t)z * C_ + c8 * 8);
    uint2 r;
    r.x = qv.x & mv.x;
    r.y = qv.y & mv.y;
    *(uint2*)(att + ((size_t)z * NPIX + n) * 512 + c8 * 8) = r;
}

// ---------------- fused i8 MFMA GEMM, dbuf BK=64, wave-local LIF, BN fused ----------------
// Round-7 post-mortem: B-direct refuted twice (rounds 1,7) -> B stays LDS-staged; this is
// the round-6 GEMM structure with ONE change.  Round-6 counters showed VALUBusy 40% >
// MfmaUtil 26% and 1.05M LDS bank conflicts: the 4-phase LDS/8-barrier LIF-transpose
// epilogue was a large minority of block life.  Fix: re-map the 8 waves from (oh,zz) =
// 32o x 64p x 1z to (oh,pq) = 32o x 16p x 4z.  Per-wave LDS reads/step unchanged (8KB:
// A 4KB + B 4KB -- the optimum 128*o_w + 64*p_w*z_w is flat in the p/z split at o_w=32);
// staging, grid, MFMA count identical.  But each thread now holds ALL 4 timesteps of its
// outputs in acc regs -> LIF runs in-register: 0 barriers, 0 LDS, 0 bank conflicts in the
// epilogue; spikes packed 4-per-u32 store (32 byte-stores -> 8 dword-stores); vh = f32x4.
// 512 thr = 8 waves; block tile 64o x 64p x 4z; LDS 2 stages x 24KB; 2 blocks/CU.
// 1-D grid, XCD-swizzled: id = px + 4*b + 64*oy.
// mode 0: spikes only; 1: f32 y(+res) AND spikes; 2: f32(+res) only.
// vhout (qkv only): v-section (o0>=1024) spikes also stored as f32 [z][h][n][64].
__global__ __launch_bounds__(512, 4) void gemm_fused_kernel(
        const u8* __restrict__ S,      // [64][256][Cin] u8 spikes
        const char* __restrict__ Wd1,  // [Cout][Cin] high digit
        const char* __restrict__ Wd0,  // [Cout][Cin] low digit
        const float2* __restrict__ AB, // [Cout] folded (A,B) coefs
        const float* res,              // [z][Cout][256] or null (may alias yout)
        float* yout,                   // [z][Cout][256] (modes 1,2)
        u8* spkout,                    // [z][n][Cout]   (modes 0,1)
        float* vhout,                  // vh f32 out or null
        int Cin, int Cout, int mode) {
    __shared__ __align__(16) char lds[49152];   // 2 stages x (Ad1 4K | Ad0 4K | B 16K)
    const int tid  = threadIdx.x;
    const int lane = tid & 63;
    const int w    = tid >> 6;           // wave index 0..7
    const int oh   = w >> 2;             // o-half (0,1)
    const int pq   = w & 3;              // p-quarter (16 pixels)
    const int r15 = lane & 15, quad = lane >> 4;
    const int id = blockIdx.x;
    const int b  = (id >> 2) & 15;
    const int o0 = (id >> 6) * 64;
    const int p0 = (id & 3) * 64;

    i32x4 acc1[4][2], acc2[4][2];        // [z][mt]
    #pragma unroll
    for (int a = 0; a < 4; ++a)
        #pragma unroll
        for (int c = 0; c < 2; ++c) {
            acc1[a][c] = (i32x4){0, 0, 0, 0};
            acc2[a][c] = (i32x4){0, 0, 0, 0};
        }

    const int srow = lane >> 2;   // staging row within 16-row group (0..15)
    const int sj   = lane & 3;    // staging 16B chunk slot (0..3)

    // ---- hoisted staging sources (advance by +64 bytes per BK=64); 3 loads/thread ----
    const char* ssrc[3];
    int sdst[3];
    #pragma unroll
    for (int e = 0; e < 3; ++e) {
        int g = w * 3 + e;              // 0..23 (wave-uniform branch)
        if (g < 4) {                    // Ad1: 64 rows x 64B
            int m = g * 16 + srow;
            ssrc[e] = Wd1 + (size_t)(o0 + m) * Cin + ((sj ^ ((m >> 1) & 3)) << 4);
            sdst[e] = g * 1024;
        } else if (g < 8) {             // Ad0
            int m = (g - 4) * 16 + srow;
            ssrc[e] = Wd0 + (size_t)(o0 + m) * Cin + ((sj ^ ((m >> 1) & 3)) << 4);
            sdst[e] = 4096 + (g - 4) * 1024;
        } else {                        // B: 256 rows = 4z x 64p, 64B each
            int r = (g - 8) * 16 + srow;
            int t = r >> 6, p = r & 63;
            ssrc[e] = (const char*)S + ((size_t)((t * B_ + b) * NPIX + p0 + p)) * Cin
                      + ((sj ^ ((r >> 1) & 3)) << 4);
            sdst[e] = 8192 + (g - 8) * 1024;
        }
    }

    auto stage = [&](int k0, int st) {
        #pragma unroll
        for (int e = 0; e < 3; ++e) {
            __builtin_amdgcn_global_load_lds(
                (const __attribute__((address_space(1))) void*)(uintptr_t)(const void*)(ssrc[e] + k0),
                (__attribute__((address_space(3))) void*)(uintptr_t)(void*)(lds + st * 24576 + sdst[e]),
                16, 0, 0);
        }
    };

    // ---- hoisted ds_read offsets (wave's 32-row A half; own p-quarter, all 4 z for B) ----
    int offA[2], offL[2], offB[4];
    #pragma unroll
    for (int mt = 0; mt < 2; ++mt) {
        int m = oh * 32 + mt * 16 + r15;
        offA[mt] = m * 64 + ((quad ^ ((m >> 1) & 3)) << 4);
        offL[mt] = 4096 + offA[mt];
    }
    #pragma unroll
    for (int z = 0; z < 4; ++z) {
        int r = z * 64 + pq * 16 + r15;
        offB[z] = 8192 + r * 64 + ((quad ^ ((r >> 1) & 3)) << 4);
    }

    auto compute = [&](int bufbase) {
        i32x4 af[2], al[2], bf[4];
        #pragma unroll
        for (int mt = 0; mt < 2; ++mt) {
            af[mt] = *(const i32x4*)(lds + bufbase + offA[mt]);
            al[mt] = *(const i32x4*)(lds + bufbase + offL[mt]);
        }
        #pragma unroll
        for (int z = 0; z < 4; ++z)
            bf[z] = *(const i32x4*)(lds + bufbase + offB[z]);
        #pragma unroll
        for (int z = 0; z < 4; ++z)
            #pragma unroll
            for (int mt = 0; mt < 2; ++mt) {
                acc1[z][mt] = __builtin_amdgcn_mfma_i32_16x16x64_i8(af[mt], bf[z], acc1[z][mt], 0, 0, 0);
                acc2[z][mt] = __builtin_amdgcn_mfma_i32_16x16x64_i8(al[mt], bf[z], acc2[z][mt], 0, 0, 0);
            }
    };

    const int nIter = Cin >> 6;   // 8 or 32, always even
    stage(0, 0);
    int k = 64;
    for (int i = 0; i < nIter; i += 2) {
        __syncthreads();
        if (i + 1 < nIter) stage(k, 1);
        k += 64;
        compute(0);
        __syncthreads();
        if (i + 2 < nIter) stage(k, 0);
        k += 64;
        compute(24576);
    }

    // ---- epilogue: combine digits + folded BN (+res); LIF over z in registers ----
    const int p = p0 + pq * 16 + r15;
    float av[2][4], bc[2][4];
    #pragma unroll
    for (int mt = 0; mt < 2; ++mt)
        #pragma unroll
        for (int r = 0; r < 4; ++r) {
            float2 abv = AB[o0 + oh * 32 + mt * 16 + quad * 4 + r];
            av[mt][r] = abv.x; bc[mt][r] = abv.y;
        }
    f32x4 yv[4][2];   // [z][mt]
    #pragma unroll
    for (int z = 0; z < 4; ++z) {
        int zt = z * B_ + b;
        #pragma unroll
        for (int mt = 0; mt < 2; ++mt) {
            int obl = o0 + oh * 32 + mt * 16 + quad * 4;
            #pragma unroll
            for (int r = 0; r < 4; ++r) {
                int qi = (acc1[z][mt][r] << 8) + acc2[z][mt][r];   // exact, < 2^24
                float val = fmaf((float)qi, av[mt][r], bc[mt][r]);
                if (mode != 0)
                    val += res[((size_t)zt * Cout + obl + r) * NPIX + p];
                yv[z][mt][r] = val;
            }
        }
    }
    if (mode != 0) {
        #pragma unroll
        for (int z = 0; z < 4; ++z) {
            int zt = z * B_ + b;
            #pragma unroll
            for (int mt = 0; mt < 2; ++mt) {
                int obl = o0 + oh * 32 + mt * 16 + quad * 4;
                #pragma unroll
                for (int r = 0; r < 4; ++r)
                    yout[((size_t)zt * Cout + obl + r) * NPIX + p] = yv[z][mt][r];
            }
        }
    }
    if (mode != 2) {
        const bool dovh = (vhout != nullptr) && (o0 >= 1024);
        const int hsec = (o0 - 1024) >> 6;
        #pragma unroll
        for (int mt = 0; mt < 2; ++mt) {
            int obl = o0 + oh * 32 + mt * 16 + quad * 4;
            uint pk0 = 0, pk1 = 0, pk2 = 0, pk3 = 0;
            f32x4 vh0, vh1, vh2, vh3;
            #pragma unroll
            for (int r = 0; r < 4; ++r) {
                float v = 0.0f;
                uint s0, s1, s2, s3;
                float x0 = yv[0][mt][r];
                v = v + (x0 - v) * 0.5f; s0 = 0; if (v >= 1.0f) { s0 = 1; v = 0.0f; }
                float x1 = yv[1][mt][r];
                v = v + (x1 - v) * 0.5f; s1 = 0; if (v >= 1.0f) { s1 = 1; v = 0.0f; }
                float x2 = yv[2][mt][r];
                v = v + (x2 - v) * 0.5f; s2 = 0; if (v >= 1.0f) { s2 = 1; v = 0.0f; }
                float x3 = yv[3][mt][r];
                v = v + (x3 - v) * 0.5f; s3 = 0; if (v >= 1.0f) { s3 = 1; v = 0.0f; }
                pk0 |= s0 << (8 * r); pk1 |= s1 << (8 * r);
                pk2 |= s2 << (8 * r); pk3 |= s3 << (8 * r);
                vh0[r] = (float)s0; vh1[r] = (float)s1;
                vh2[r] = (float)s2; vh3[r] = (float)s3;
            }
            uint pks[4] = {pk0, pk1, pk2, pk3};
            f32x4 vhs[4] = {vh0, vh1, vh2, vh3};
            #pragma unroll
            for (int t = 0; t < 4; ++t) {
                *(uint*)(spkout + ((size_t)((t * B_ + b) * NPIX + p)) * Cout + obl) = pks[t];
                if (dovh)
                    *(f32x4*)(vhout + ((((size_t)(t * B_ + b)) * 8 + hsec) * NPIX + p) * 64
                              + (obl - o0)) = vhs[t];
            }
        }
    }
}

extern "C" void kernel_launch(void* const* d_in, const int* in_sizes, int n_in,
                              void* d_out, int out_size, void* d_ws, size_t ws_size,
                              hipStream_t stream) {
    (void)in_sizes; (void)n_in; (void)out_size; (void)ws_size;
    const float* x       = (const float*)d_in[0];
    const float* q_w     = (const float*)d_in[1];
    const float* k_w     = (const float*)d_in[2];
    const float* v_w     = (const float*)d_in[3];
    const float* proj_w  = (const float*)d_in[4];
    const float* proj_b  = (const float*)d_in[5];
    const float* fc1_w   = (const float*)d_in[6];
    const float* fc1_b   = (const float*)d_in[7];
    const float* fc2_w   = (const float*)d_in[8];
    const float* fc2_b   = (const float*)d_in[9];
    const float* q_bn    = (const float*)d_in[10];
    const float* k_bn    = (const float*)d_in[11];
    const float* v_bn    = (const float*)d_in[12];
    const float* proj_bn = (const float*)d_in[13];
    const float* fc1_bn  = (const float*)d_in[14];
    const float* fc2_bn  = (const float*)d_in[15];

    char* ws = (char*)d_ws;
    float2* abb   = (float2*)(ws + OFF_AB);
    int*   presum4 = (int*)(ws + OFF_PRESUM);
    u8*    maskp   = (u8*)(ws + OFF_MASK);
    const char *qkv1 = ws + OFF_QKV1, *qkv0 = ws + OFF_QKV0;
    const char *p1 = ws + OFF_P1,   *p0d = ws + OFF_P0;
    const char *f11 = ws + OFF_F11, *f10 = ws + OFF_F10;
    const char *f21 = ws + OFF_F21, *f20 = ws + OFF_F20;
    u8* spkA   = (u8*)(ws + OFF_SPK_A);    // xs -> att
    u8* spkQKV = (u8*)(ws + OFF_SPK_QKV);  // [z][n][1536]
    u8* spkE   = (u8*)(ws + OFF_SPK_E);    // h1
    u8* h2     = (u8*)(ws + OFF_H2);       // h2 [z][n][2048]

    float* out1 = (float*)d_out;
    float* out2 = out1 + 8388608;
    float* x_attn = out1;                 // x_attn lives in out1 until fc2 overwrites in-place

    // prep: quantize all weights + fold BN (1 launch)
    prep_quant_kernel<<<1152, 256, 0, stream>>>(q_w, k_w, v_w, proj_w, fc1_w, fc2_w,
                                                q_bn, k_bn, v_bn, proj_bn, fc1_bn, fc2_bn,
                                                proj_b, fc1_b, fc2_b, ws);

    dim3 gLT(4, 8, 16);       // lif_transpose on x (Cf=512)

    // shortcut LIF on x -> xs spikes [z][n][c] u8
    lif_transpose_kernel<<<gLT, 256, 0, stream>>>(x, spkA, C_);

    // q+k+v fused: GEMM+BN+LIF -> spikes [z][n][1536]; v-section also writes vh f32 (out2)
    gemm_fused_kernel<<<24 * 64, 512, 0, stream>>>(spkA, qkv1, qkv0, abb,
                                                   nullptr, nullptr, spkQKV, out2, C_, 1536, 0);

    // kv reduce + talking-heads LIF + att mask
    kv_presum_kernel<<<256, 256, 0, stream>>>(spkQKV, presum4);
    kv_lif_mask_kernel<<<32, 256, 0, stream>>>(presum4, maskp);
    att_apply_kernel<<<4096, 256, 0, stream>>>(spkQKV, maskp, spkA);   // att into A (xs dead)

    // proj: GEMM(att)+bias+BN + x residual -> x_attn f32 AND h1 spikes
    gemm_fused_kernel<<<8 * 64, 512, 0, stream>>>(spkA, p1, p0d, abb + 1536,
                                                  x, x_attn, spkE, nullptr, C_, C_, 1);

    // fc1: GEMM+bias+BN+LIF -> h2 spikes
    gemm_fused_kernel<<<32 * 64, 512, 0, stream>>>(spkE, f11, f10, abb + 2048,
                                                   nullptr, nullptr, h2, nullptr, C_, HID_, 0);

    // fc2: GEMM+bias+BN + x_attn residual -> out1 (in place over x_attn)
    gemm_fused_kernel<<<8 * 64, 512, 0, stream>>>(h2, f21, f20, abb + 4096,
                                                  x_attn, out1, nullptr, nullptr, HID_, C_, 2);
}

// Round 9
// 298.296 us; speedup vs baseline: 1.3459x; 1.0115x over previous
//
#include <hip/hip_runtime.h>
#include <stdint.h>

#pragma clang fp contract(off)

typedef int i32x4 __attribute__((ext_vector_type(4)));
typedef float f32x4 __attribute__((ext_vector_type(4)));
typedef unsigned char u8;

#define T_   4
#define B_   16
#define C_   512
#define HID_ 2048
#define NPIX 256
#define Z_   64            // T_*B_

// ---------------- workspace layout (bytes) ----------------
// AB coef: float2 per output row, rows ordered qkv(1536) proj(512) fc1(2048) fc2(512)
constexpr size_t OFF_AB      = 0;                        // 4608*8 = 36864
constexpr size_t OFF_PRESUM  = 65536;                    // 4*64*512 i32 = 512KB
constexpr size_t OFF_MASK    = OFF_PRESUM + 524288;      // u8[64][512] = 32KB
constexpr size_t OFF_WD      = OFF_MASK + 65536;
constexpr size_t SZ_QKVD = 1536*512;
constexpr size_t SZ_PD   = 512*512;
constexpr size_t SZ_F1D  = 2048*512;
constexpr size_t SZ_F2D  = 512*2048;
constexpr size_t OFF_QKV1 = OFF_WD;
constexpr size_t OFF_QKV0 = OFF_QKV1 + SZ_QKVD;
constexpr size_t OFF_P1   = OFF_QKV0 + SZ_QKVD;
constexpr size_t OFF_P0   = OFF_P1 + SZ_PD;
constexpr size_t OFF_F11  = OFF_P0 + SZ_PD;
constexpr size_t OFF_F10  = OFF_F11 + SZ_F1D;
constexpr size_t OFF_F21  = OFF_F10 + SZ_F1D;
constexpr size_t OFF_F20  = OFF_F21 + SZ_F2D;
constexpr size_t SPKB8    = (size_t)64*256*512;          // 8MB per 512-ch spike tensor
constexpr size_t OFF_SPK_A   = (OFF_F20 + SZ_F2D + 255) & ~(size_t)255;  // xs -> att (u8)
constexpr size_t OFF_SPK_QKV = OFF_SPK_A + SPKB8;        // [z][n][1536] u8 (24MB)
constexpr size_t OFF_SPK_E   = OFF_SPK_QKV + 3*SPKB8;    // h1 (8MB)
constexpr size_t OFF_H2      = OFF_SPK_E + SPKB8;        // h2 [z][n][2048] u8 (32MB)

// ---------------- prep: per-row absmax -> pow2 scale -> 2-digit i8 quant + folded BN ----------------
// One wave per output row.  w ~= (d1*256 + d0)/S with S = 2^sh chosen so max|w|*S <= 32639.
// Exact i32 accumulation downstream; only error is weight rounding <= 0.5/S.
// Folded epilogue coefs: val = q_total * A + B,  A = sc/S,  B = (bias - m)*sc + beta.
__global__ __launch_bounds__(256) void prep_quant_kernel(
        const float* __restrict__ q_w, const float* __restrict__ k_w,
        const float* __restrict__ v_w, const float* __restrict__ p_w,
        const float* __restrict__ f1_w, const float* __restrict__ f2_w,
        const float* __restrict__ q_bn, const float* __restrict__ k_bn,
        const float* __restrict__ v_bn, const float* __restrict__ p_bn,
        const float* __restrict__ f1_bn, const float* __restrict__ f2_bn,
        const float* __restrict__ p_b, const float* __restrict__ f1_b,
        const float* __restrict__ f2_b, char* ws) {
    int wv = threadIdx.x >> 6, lane = threadIdx.x & 63;
    int r = blockIdx.x * 4 + wv;            // 0..4607
    const float* wsrc; const float* bn; const float* bias;
    char *d1, *d0; int Cin, Cn, o;
    if (r < 512)        { o=r;       wsrc=q_w  + (size_t)o*512;  bn=q_bn;  bias=nullptr; Cin=512;  Cn=512;
                          d1=ws+OFF_QKV1+(size_t)r*512;      d0=ws+OFF_QKV0+(size_t)r*512; }
    else if (r < 1024)  { o=r-512;   wsrc=k_w  + (size_t)o*512;  bn=k_bn;  bias=nullptr; Cin=512;  Cn=512;
                          d1=ws+OFF_QKV1+(size_t)r*512;      d0=ws+OFF_QKV0+(size_t)r*512; }
    else if (r < 1536)  { o=r-1024;  wsrc=v_w  + (size_t)o*512;  bn=v_bn;  bias=nullptr; Cin=512;  Cn=512;
                          d1=ws+OFF_QKV1+(size_t)r*512;      d0=ws+OFF_QKV0+(size_t)r*512; }
    else if (r < 2048)  { o=r-1536;  wsrc=p_w  + (size_t)o*512;  bn=p_bn;  bias=p_b;     Cin=512;  Cn=512;
                          d1=ws+OFF_P1+(size_t)o*512;        d0=ws+OFF_P0+(size_t)o*512; }
    else if (r < 4096)  { o=r-2048;  wsrc=f1_w + (size_t)o*512;  bn=f1_bn; bias=f1_b;    Cin=512;  Cn=2048;
                          d1=ws+OFF_F11+(size_t)o*512;       d0=ws+OFF_F10+(size_t)o*512; }
    else if (r < 4608)  { o=r-4096;  wsrc=f2_w + (size_t)o*2048; bn=f2_bn; bias=f2_b;    Cin=2048; Cn=512;
                          d1=ws+OFF_F21+(size_t)o*2048;      d0=ws+OFF_F20+(size_t)o*2048; }
    else return;

    float mx = 0.0f;
    for (int c = lane; c < Cin; c += 64) mx = fmaxf(mx, fabsf(wsrc[c]));
    #pragma unroll
    for (int off = 32; off; off >>= 1) mx = fmaxf(mx, __shfl_xor(mx, off));

    int E; float mant = frexpf(mx, &E);          // mx = mant*2^E, mant in [0.5,1)
    int sh = (ldexpf(mant, 15) > 32639.0f) ? (14 - E) : (15 - E);
    if (mx == 0.0f) sh = 0;
    float S = ldexpf(1.0f, sh);

    for (int c = lane; c < Cin; c += 64) {
        int q = __float2int_rn(wsrc[c] * S);
        int t0 = ((q + 128) & 255) - 128;        // low digit in [-128,127]
        int t1 = (q - t0) >> 8;                  // high digit, exact, in [-128,127]
        d0[c] = (char)t0;
        d1[c] = (char)t1;
    }
    if (lane == 0) {
        float g  = bn[o];
        float be = bn[Cn + o];
        float m  = bn[2 * Cn + o];
        float vv = bn[3 * Cn + o];
        float sc = g / sqrtf(vv + 1e-5f);
        float bv = bias ? bias[o] : 0.0f;
        float2* ab = (float2*)(ws + OFF_AB) + r;
        *ab = make_float2(sc * ldexpf(1.0f, -sh), (bv - m) * sc + be);
    }
}

// ---------------- LIF + transpose: y[T,B,Cf,N] f32 -> spk[z][n][c] u8 ----------------
__global__ __launch_bounds__(256) void lif_transpose_kernel(
        const float* __restrict__ y, u8* __restrict__ spk, int Cf) {
    __shared__ __align__(16) u8 tile[256 * 80];   // [t*64+nn][80]
    int b  = blockIdx.z;
    int c0 = blockIdx.y * 64;
    int n0 = blockIdx.x * 64;
    int tid = threadIdx.x;
    int nn = tid & 63;
    int cg = tid >> 6;
    size_t tstride = (size_t)B_ * Cf * NPIX;
    for (int e = 0; e < 16; ++e) {
        int ci = cg * 16 + e;
        size_t base = ((size_t)b * Cf + c0 + ci) * NPIX + n0 + nn;
        float v = 0.0f;
        #pragma unroll
        for (int t = 0; t < T_; ++t) {
            float x = y[base + (size_t)t * tstride];
            v = v + (x - v) * 0.5f;
            u8 s = 0;
            if (v >= 1.0f) { s = 1; v = 0.0f; }
            tile[(t * 64 + nn) * 80 + ci] = s;
        }
    }
    __syncthreads();
    int t = tid >> 6, n2 = tid & 63;
    const u8* srow = &tile[(t * 64 + n2) * 80];
    u8* drow = spk + ((size_t)((t * B_ + b) * NPIX) + n0 + n2) * Cf + c0;
    #pragma unroll
    for (int kk = 0; kk < 4; ++kk)
        *(uint4*)(drow + kk * 16) = *(const uint4*)(srow + kk * 16);
}

// ---------------- kv presum: integer counts of (k&v) over n-quarter (u8 spikes) ----------------
__global__ void kv_presum_kernel(const u8* __restrict__ qkv, int* __restrict__ presum4) {
    int z  = blockIdx.x >> 2;
    int nq = blockIdx.x & 3;
    int tid = threadIdx.x;
    if (tid >= 128) return;                       // 128 uints cover 512 k-channels
    const uint* base = (const uint*)(qkv + (size_t)z * NPIX * 1536 + (size_t)nq * 64 * 1536);
    int s0 = 0, s1 = 0, s2 = 0, s3 = 0;
    for (int n = 0; n < 64; ++n) {
        uint a = base[n * 384 + 128 + tid];   // k bytes 512..1023
        uint b = base[n * 384 + 256 + tid];   // v bytes 1024..1535
        uint c = a & b;
        s0 += c & 1; s1 += (c >> 8) & 1; s2 += (c >> 16) & 1; s3 += (c >> 24) & 1;
    }
    int o = ((nq * Z_ + z) << 9) + 4 * tid;
    presum4[o] = s0; presum4[o + 1] = s1; presum4[o + 2] = s2; presum4[o + 3] = s3;
}

// ---------------- kv LIF (vth=0.5) -> mask u8 ----------------
__global__ void kv_lif_mask_kernel(const int* __restrict__ presum4, u8* __restrict__ mask) {
    int i = blockIdx.x * 256 + threadIdx.x;   // 8192 = B_*C_
    int b = i >> 9, c = i & (C_ - 1);
    float v = 0.0f;
    #pragma unroll
    for (int t = 0; t < T_; ++t) {
        int z = t * B_ + b;
        int s = presum4[(z << 9) + c] + presum4[((Z_ + z) << 9) + c]
              + presum4[((2 * Z_ + z) << 9) + c] + presum4[((3 * Z_ + z) << 9) + c];
        float x = (float)s;                   // exact integer <= 256
        v = v + (x - v) * 0.5f;
        u8 m = 0;
        if (v >= 0.5f) { m = 0xFF; v = 0.0f; }
        mask[(z << 9) + c] = m;
    }
}

// ---------------- att = q & mask (q strided 1536B, out compact 512B) ----------------
__global__ void att_apply_kernel(const u8* __restrict__ qkv, const u8* __restrict__ mask,
                                 u8* __restrict__ att) {
    size_t i = (size_t)blockIdx.x * 256 + threadIdx.x;  // over 64*256*64 uint2-groups
    int z   = (int)(i >> 14);
    int rem = (int)(i & 16383);
    int n   = rem >> 6;
    int c8  = rem & 63;
    uint2 qv = *(const uint2*)(qkv + ((size_t)z * NPIX + n) * 1536 + c8 * 8);
    uint2 mv = *(const uint2*)(mask + (size_t)z * C_ + c8 * 8);
    uint2 r;
    r.x = qv.x & mv.x;
    r.y = qv.y & mv.y;
    *(uint2*)(att + ((size_t)z * NPIX + n) * 512 + c8 * 8) = r;
}

// ---------------- fused i8 MFMA GEMM, dbuf BK=64, in-reg LIF + coalesced stores ----------------
// Round-8 post-mortem: wave-local LIF killed the bank conflicts (1.05M->0) and 6 barriers,
// but the per-lane uint stores at pixel-stride 2048B write-amplified HBM (qkv 40->46.5MB)
// and vh f32x4 landed at 256B stride.  This round keeps the round-8 K-loop and in-register
// LIF and routes ONLY the stores through a 2-barrier byte-transpose in LDS (stage buffers
// are dead after the K-loop): threads write uint-packed spikes into [4z*64p][80] (2-way
// bank alias max = free), then 512 threads read 32B each and store FULL 64B lines to
// spkout; v-section emits vh as 128B-contiguous f32x4 runs.
// 512 thr = 8 waves, wave w = (oh=w>>2 o-half, pq=w&3 p-quarter); block tile 64o x 64p x 4z;
// LDS 2 stages x 24KB; 2 blocks/CU.  B stays LDS-staged (B-direct refuted rounds 1,7).
// 1-D grid, XCD-swizzled: id = px + 4*b + 64*oy.
// mode 0: spikes only; 1: f32 y(+res) AND spikes; 2: f32(+res) only.
// vhout (qkv only): v-section (o0>=1024) spikes also stored as f32 [z][h][n][64].
__global__ __launch_bounds__(512, 4) void gemm_fused_kernel(
        const u8* __restrict__ S,      // [64][256][Cin] u8 spikes
        const char* __restrict__ Wd1,  // [Cout][Cin] high digit
        const char* __restrict__ Wd0,  // [Cout][Cin] low digit
        const float2* __restrict__ AB, // [Cout] folded (A,B) coefs
        const float* res,              // [z][Cout][256] or null (may alias yout)
        float* yout,                   // [z][Cout][256] (modes 1,2)
        u8* spkout,                    // [z][n][Cout]   (modes 0,1)
        float* vhout,                  // vh f32 out or null
        int Cin, int Cout, int mode) {
    __shared__ __align__(16) char lds[49152];   // 2 stages x (Ad1 4K | Ad0 4K | B 16K)
    const int tid  = threadIdx.x;
    const int lane = tid & 63;
    const int w    = tid >> 6;           // wave index 0..7
    const int oh   = w >> 2;             // o-half (0,1)
    const int pq   = w & 3;              // p-quarter (16 pixels)
    const int r15 = lane & 15, quad = lane >> 4;
    const int id = blockIdx.x;
    const int b  = (id >> 2) & 15;
    const int o0 = (id >> 6) * 64;
    const int p0 = (id & 3) * 64;

    i32x4 acc1[4][2], acc2[4][2];        // [z][mt]
    #pragma unroll
    for (int a = 0; a < 4; ++a)
        #pragma unroll
        for (int c = 0; c < 2; ++c) {
            acc1[a][c] = (i32x4){0, 0, 0, 0};
            acc2[a][c] = (i32x4){0, 0, 0, 0};
        }

    const int srow = lane >> 2;   // staging row within 16-row group (0..15)
    const int sj   = lane & 3;    // staging 16B chunk slot (0..3)

    // ---- hoisted staging sources (advance by +64 bytes per BK=64); 3 loads/thread ----
    const char* ssrc[3];
    int sdst[3];
    #pragma unroll
    for (int e = 0; e < 3; ++e) {
        int g = w * 3 + e;              // 0..23 (wave-uniform branch)
        if (g < 4) {                    // Ad1: 64 rows x 64B
            int m = g * 16 + srow;
            ssrc[e] = Wd1 + (size_t)(o0 + m) * Cin + ((sj ^ ((m >> 1) & 3)) << 4);
            sdst[e] = g * 1024;
        } else if (g < 8) {             // Ad0
            int m = (g - 4) * 16 + srow;
            ssrc[e] = Wd0 + (size_t)(o0 + m) * Cin + ((sj ^ ((m >> 1) & 3)) << 4);
            sdst[e] = 4096 + (g - 4) * 1024;
        } else {                        // B: 256 rows = 4z x 64p, 64B each
            int r = (g - 8) * 16 + srow;
            int t = r >> 6, p = r & 63;
            ssrc[e] = (const char*)S + ((size_t)((t * B_ + b) * NPIX + p0 + p)) * Cin
                      + ((sj ^ ((r >> 1) & 3)) << 4);
            sdst[e] = 8192 + (g - 8) * 1024;
        }
    }

    auto stage = [&](int k0, int st) {
        #pragma unroll
        for (int e = 0; e < 3; ++e) {
            __builtin_amdgcn_global_load_lds(
                (const __attribute__((address_space(1))) void*)(uintptr_t)(const void*)(ssrc[e] + k0),
                (__attribute__((address_space(3))) void*)(uintptr_t)(void*)(lds + st * 24576 + sdst[e]),
                16, 0, 0);
        }
    };

    // ---- hoisted ds_read offsets (wave's 32-row A half; own p-quarter, all 4 z for B) ----
    int offA[2], offL[2], offB[4];
    #pragma unroll
    for (int mt = 0; mt < 2; ++mt) {
        int m = oh * 32 + mt * 16 + r15;
        offA[mt] = m * 64 + ((quad ^ ((m >> 1) & 3)) << 4);
        offL[mt] = 4096 + offA[mt];
    }
    #pragma unroll
    for (int z = 0; z < 4; ++z) {
        int r = z * 64 + pq * 16 + r15;
        offB[z] = 8192 + r * 64 + ((quad ^ ((r >> 1) & 3)) << 4);
    }

    auto compute = [&](int bufbase) {
        i32x4 af[2], al[2], bf[4];
        #pragma unroll
        for (int mt = 0; mt < 2; ++mt) {
            af[mt] = *(const i32x4*)(lds + bufbase + offA[mt]);
            al[mt] = *(const i32x4*)(lds + bufbase + offL[mt]);
        }
        #pragma unroll
        for (int z = 0; z < 4; ++z)
            bf[z] = *(const i32x4*)(lds + bufbase + offB[z]);
        #pragma unroll
        for (int z = 0; z < 4; ++z)
            #pragma unroll
            for (int mt = 0; mt < 2; ++mt) {
                acc1[z][mt] = __builtin_amdgcn_mfma_i32_16x16x64_i8(af[mt], bf[z], acc1[z][mt], 0, 0, 0);
                acc2[z][mt] = __builtin_amdgcn_mfma_i32_16x16x64_i8(al[mt], bf[z], acc2[z][mt], 0, 0, 0);
            }
    };

    const int nIter = Cin >> 6;   // 8 or 32, always even
    stage(0, 0);
    int k = 64;
    for (int i = 0; i < nIter; i += 2) {
        __syncthreads();
        if (i + 1 < nIter) stage(k, 1);
        k += 64;
        compute(0);
        __syncthreads();
        if (i + 2 < nIter) stage(k, 0);
        k += 64;
        compute(24576);
    }

    // ---- epilogue: combine digits + folded BN (+res) ----
    const int p = p0 + pq * 16 + r15;
    float av[2][4], bc[2][4];
    #pragma unroll
    for (int mt = 0; mt < 2; ++mt)
        #pragma unroll
        for (int r = 0; r < 4; ++r) {
            float2 abv = AB[o0 + oh * 32 + mt * 16 + quad * 4 + r];
            av[mt][r] = abv.x; bc[mt][r] = abv.y;
        }
    f32x4 yv[4][2];   // [z][mt]
    #pragma unroll
    for (int z = 0; z < 4; ++z) {
        int zt = z * B_ + b;
        #pragma unroll
        for (int mt = 0; mt < 2; ++mt) {
            int obl = o0 + oh * 32 + mt * 16 + quad * 4;
            #pragma unroll
            for (int r = 0; r < 4; ++r) {
                int qi = (acc1[z][mt][r] << 8) + acc2[z][mt][r];   // exact, < 2^24
                float val = fmaf((float)qi, av[mt][r], bc[mt][r]);
                if (mode != 0)
                    val += res[((size_t)zt * Cout + obl + r) * NPIX + p];
                yv[z][mt][r] = val;
            }
        }
    }
    if (mode != 0) {
        #pragma unroll
        for (int z = 0; z < 4; ++z) {
            int zt = z * B_ + b;
            #pragma unroll
            for (int mt = 0; mt < 2; ++mt) {
                int obl = o0 + oh * 32 + mt * 16 + quad * 4;
                #pragma unroll
                for (int r = 0; r < 4; ++r)
                    yout[((size_t)zt * Cout + obl + r) * NPIX + p] = yv[z][mt][r];
            }
        }
    }
    if (mode != 2) {
        const bool dovh = (vhout != nullptr) && (o0 >= 1024);
        const int hsec = (o0 - 1024) >> 6;
        // LIF over z in registers, pack 4 channels per uint
        uint pk[4][2];   // [z][mt]
        #pragma unroll
        for (int z = 0; z < 4; ++z) { pk[z][0] = 0; pk[z][1] = 0; }
        #pragma unroll
        for (int mt = 0; mt < 2; ++mt)
            #pragma unroll
            for (int r = 0; r < 4; ++r) {
                float v = 0.0f;
                #pragma unroll
                for (int z = 0; z < 4; ++z) {
                    v = v + (yv[z][mt][r] - v) * 0.5f;
                    uint s = 0;
                    if (v >= 1.0f) { s = 1; v = 0.0f; }
                    pk[z][mt] |= s << (8 * r);
                }
            }
        // byte-transpose through LDS (stage buffers dead) for full-line global stores
        __syncthreads();
        u8* spkb = (u8*)lds;                 // [4*64][80]
        const int pl = pq * 16 + r15;
        #pragma unroll
        for (int z = 0; z < 4; ++z)
            #pragma unroll
            for (int mt = 0; mt < 2; ++mt)
                *(uint*)(spkb + (z * 64 + pl) * 80 + oh * 32 + mt * 16 + quad * 4) = pk[z][mt];
        __syncthreads();
        {
            int row = tid >> 1, half = tid & 1;    // row: z*64+p, 32B per thread
            int z = row >> 6, p2 = row & 63;
            const u8* src = spkb + row * 80 + half * 32;
            uint4 wa = *(const uint4*)src;
            uint4 wb = *(const uint4*)(src + 16);
            size_t gb = ((size_t)((z * B_ + b) * NPIX + p0 + p2)) * Cout + o0 + half * 32;
            *(uint4*)(spkout + gb) = wa;
            *(uint4*)(spkout + gb + 16) = wb;
            if (dovh) {
                float* vdst = vhout + (((size_t)(z * B_ + b) * 8 + hsec) * NPIX + p0 + p2) * 64
                              + half * 32;
                uint wd[8] = {wa.x, wa.y, wa.z, wa.w, wb.x, wb.y, wb.z, wb.w};
                #pragma unroll
                for (int wi = 0; wi < 8; ++wi) {
                    f32x4 vf;
                    #pragma unroll
                    for (int bb = 0; bb < 4; ++bb)
                        vf[bb] = (float)((wd[wi] >> (8 * bb)) & 1);
                    *(f32x4*)(vdst + wi * 4) = vf;
                }
            }
        }
    }
}

extern "C" void kernel_launch(void* const* d_in, const int* in_sizes, int n_in,
                              void* d_out, int out_size, void* d_ws, size_t ws_size,
                              hipStream_t stream) {
    (void)in_sizes; (void)n_in; (void)out_size; (void)ws_size;
    const float* x       = (const float*)d_in[0];
    const float* q_w     = (const float*)d_in[1];
    const float* k_w     = (const float*)d_in[2];
    const float* v_w     = (const float*)d_in[3];
    const float* proj_w  = (const float*)d_in[4];
    const float* proj_b  = (const float*)d_in[5];
    const float* fc1_w   = (const float*)d_in[6];
    const float* fc1_b   = (const float*)d_in[7];
    const float* fc2_w   = (const float*)d_in[8];
    const float* fc2_b   = (const float*)d_in[9];
    const float* q_bn    = (const float*)d_in[10];
    const float* k_bn    = (const float*)d_in[11];
    const float* v_bn    = (const float*)d_in[12];
    const float* proj_bn = (const float*)d_in[13];
    const float* fc1_bn  = (const float*)d_in[14];
    const float* fc2_bn  = (const float*)d_in[15];

    char* ws = (char*)d_ws;
    float2* abb   = (float2*)(ws + OFF_AB);
    int*   presum4 = (int*)(ws + OFF_PRESUM);
    u8*    maskp   = (u8*)(ws + OFF_MASK);
    const char *qkv1 = ws + OFF_QKV1, *qkv0 = ws + OFF_QKV0;
    const char *p1 = ws + OFF_P1,   *p0d = ws + OFF_P0;
    const char *f11 = ws + OFF_F11, *f10 = ws + OFF_F10;
    const char *f21 = ws + OFF_F21, *f20 = ws + OFF_F20;
    u8* spkA   = (u8*)(ws + OFF_SPK_A);    // xs -> att
    u8* spkQKV = (u8*)(ws + OFF_SPK_QKV);  // [z][n][1536]
    u8* spkE   = (u8*)(ws + OFF_SPK_E);    // h1
    u8* h2     = (u8*)(ws + OFF_H2);       // h2 [z][n][2048]

    float* out1 = (float*)d_out;
    float* out2 = out1 + 8388608;
    float* x_attn = out1;                 // x_attn lives in out1 until fc2 overwrites in-place

    // prep: quantize all weights + fold BN (1 launch)
    prep_quant_kernel<<<1152, 256, 0, stream>>>(q_w, k_w, v_w, proj_w, fc1_w, fc2_w,
                                                q_bn, k_bn, v_bn, proj_bn, fc1_bn, fc2_bn,
                                                proj_b, fc1_b, fc2_b, ws);

    dim3 gLT(4, 8, 16);       // lif_transpose on x (Cf=512)

    // shortcut LIF on x -> xs spikes [z][n][c] u8
    lif_transpose_kernel<<<gLT, 256, 0, stream>>>(x, spkA, C_);

    // q+k+v fused: GEMM+BN+LIF -> spikes [z][n][1536]; v-section also writes vh f32 (out2)
    gemm_fused_kernel<<<24 * 64, 512, 0, stream>>>(spkA, qkv1, qkv0, abb,
                                                   nullptr, nullptr, spkQKV, out2, C_, 1536, 0);

    // kv reduce + talking-heads LIF + att mask
    kv_presum_kernel<<<256, 256, 0, stream>>>(spkQKV, presum4);
    kv_lif_mask_kernel<<<32, 256, 0, stream>>>(presum4, maskp);
    att_apply_kernel<<<4096, 256, 0, stream>>>(spkQKV, maskp, spkA);   // att into A (xs dead)

    // proj: GEMM(att)+bias+BN + x residual -> x_attn f32 AND h1 spikes
    gemm_fused_kernel<<<8 * 64, 512, 0, stream>>>(spkA, p1, p0d, abb + 1536,
                                                  x, x_attn, spkE, nullptr, C_, C_, 1);

    // fc1: GEMM+bias+BN+LIF -> h2 spikes
    gemm_fused_kernel<<<32 * 64, 512, 0, stream>>>(spkE, f11, f10, abb + 2048,
                                                   nullptr, nullptr, h2, nullptr, C_, HID_, 0);

    // fc2: GEMM+bias+BN + x_attn residual -> out1 (in place over x_attn)
    gemm_fused_kernel<<<8 * 64, 512, 0, stream>>>(h2, f21, f20, abb + 4096,
                                                  x_attn, out1, nullptr, nullptr, HID_, C_, 2);
}